// Round 12
// baseline (280.460 us; speedup 1.0000x reference)
//
#include <hip/hip_runtime.h>
#include <hip/hip_bf16.h>

typedef __bf16 bf16x8 __attribute__((ext_vector_type(8)));
typedef __bf16 bf16x4 __attribute__((ext_vector_type(4)));
typedef __bf16 bf16x2 __attribute__((ext_vector_type(2)));
typedef float  f32x4  __attribute__((ext_vector_type(4)));

#define T_LEN 4096
#define QBLK  128
#define KVBLK 128
#define NKV   (T_LEN / KVBLK)   // 32

// 8 waves = 4 t-groups (32 rows, R=2 halves) x 2 s-halves. R=2 keeps r10's
// per-wave K/V-frag reuse; the s-split restores 16 waves/CU (r10 lesson:
// wave count, not LDS BW, is binding). No-max softmax makes s-partials
// additive: O_tot = O_a + O_b, l_tot = l_a + l_b -> trivial end merge.
//
// LDS map (bytes):
//   [0,     16384)  Qs : [128 t][64 c] bf16, swizzled  } [0,32768) reused as
//   [16384, 24576)  Ks0: [64 s][64 c] bf16, swizzled   } f32 Obuf in epilogue
//   [24576, 32768)  Ks1: s=64..127
//   [32768, 40960)  Vs0: [64 c][64 s-permuted] bf16    } [32768,65536) reused
//   [40960, 49152)  Vs1: s=64..127                     } as merge buf (post-loop)
//   [65536, 66048)  l-merge (128 f32)
__device__ __forceinline__ int swz(int row, int colByte) {
    return row * 128 + (colByte ^ (((row ^ (row >> 2)) & 7) << 4));
}
__device__ __forceinline__ int swzM(int row, int colByte) {   // merge buf [c][t] f32
    return row * 128 + (colByte ^ ((row & 7) << 4));
}
// f32 epilogue buffer: row = c (512B of t), XOR in 32B units
__device__ __forceinline__ int swzO(int row, int colByte) {
    return row * 512 + (colByte ^ ((row & 7) << 5));
}

// Q pre-scale: 1/8 (QK scale) x log2(e); no-max exp2 softmax (r9-verified).
#define QSCALE 0.18033688011112042f

__global__ __launch_bounds__(512, 4)
void qkv_attn_kernel(const float* __restrict__ qkv, float* __restrict__ out) {
    __shared__ __align__(16) char lds[66560];

    // T1 XCD swizzle (512 wgs = 8 XCDs x 64, bijective simple form).
    const int fid   = (blockIdx.x & 7) * 64 + (blockIdx.x >> 3);
    const int bh    = fid >> 5;     // 0..15
    const int ttile = fid & 31;     // 0..31
    const float* qp = qkv + (size_t)bh * 192 * T_LEN;
    const float* kp = qp + (size_t)64  * T_LEN;
    const float* vp = qp + (size_t)128 * T_LEN;
    const int t0 = ttile * QBLK;

    const int tid  = threadIdx.x;
    const int wave = tid >> 6, lane = tid & 63;
    const int g = lane >> 4, i = lane & 15;
    const int tg = wave >> 1, half = wave & 1;   // t-group, s-half

    // staging coordinates (loop-invariant); each thread stages one s-subtile.
    // Runtime-selected LDS bases via arithmetic (NOT a pointer array: that
    // forced an addrspacecast static initializer -> r11 compile error).
    const int ssub  = tid >> 8;            // 0/1: which 64-s subtile I stage
    char* const KsW = lds + 16384 + ssub * 8192;
    char* const VsW = lds + 32768 + ssub * 8192;
    char* const KsR = lds + 16384 + half * 8192;   // compute-side (my s-half)
    char* const VsR = lds + 32768 + half * 8192;

    const int k_sq  = (tid & 15) * 4;      // s-quad within subtile
    const int k_c16 = (tid >> 4) & 15;     // cpairs k_c16, k_c16+16
    const float* kb0 = kp + (size_t)(k_c16 * 2)        * T_LEN + ssub * 64 + k_sq;
    const float* kb1 = kp + (size_t)((k_c16 + 16) * 2) * T_LEN + ssub * 64 + k_sq;
    const int v_c  = (tid >> 2) & 63;      // channel row
    const int v_u0 = (tid & 3) * 4;        // base 4-s chunk
    const float* vbase = vp + (size_t)v_c * T_LEN + ssub * 64 + v_u0 * 4;

    // ---- stage Q^T x QSCALE : [128 t][64 c] ----
    {
        const int tq  = (tid & 31) * 4;   // 0..124
        const int cp8 = tid >> 5;         // 0..15; pairs cp8, cp8+16
        #pragma unroll
        for (int hh = 0; hh < 2; ++hh) {
            const int cpair = cp8 + hh * 16;            // 0..31
            const float* base = qp + (size_t)(cpair * 2) * T_LEN + t0 + tq;
            float4 lo = *(const float4*)(base);
            float4 hi = *(const float4*)(base + T_LEN);
            bf16x2 v;
            v[0] = (__bf16)(lo.x * QSCALE); v[1] = (__bf16)(hi.x * QSCALE);
            *(bf16x2*)(lds + swz(tq + 0, cpair * 4)) = v;
            v[0] = (__bf16)(lo.y * QSCALE); v[1] = (__bf16)(hi.y * QSCALE);
            *(bf16x2*)(lds + swz(tq + 1, cpair * 4)) = v;
            v[0] = (__bf16)(lo.z * QSCALE); v[1] = (__bf16)(hi.z * QSCALE);
            *(bf16x2*)(lds + swz(tq + 2, cpair * 4)) = v;
            v[0] = (__bf16)(lo.w * QSCALE); v[1] = (__bf16)(hi.w * QSCALE);
            *(bf16x2*)(lds + swz(tq + 3, cpair * 4)) = v;
        }
    }

    // ---- T14 register prefetch (single set): 4 K float4 + 4 V float4 ----
    float4 kreg[2][2];   // [j][lo/hi channel]
    float4 vreg[4];
    #pragma unroll
    for (int j = 0; j < 2; ++j) {
        const float* kb = j ? kb1 : kb0;
        kreg[j][0] = *(const float4*)(kb);
        kreg[j][1] = *(const float4*)(kb + T_LEN);
    }
    #pragma unroll
    for (int p = 0; p < 4; ++p) vreg[p] = *(const float4*)(vbase + p * 4);

    f32x4 oacc[2][4];
    #pragma unroll
    for (int h = 0; h < 2; ++h)
        #pragma unroll
        for (int n = 0; n < 4; ++n) oacc[h][n] = (f32x4){0.f, 0.f, 0.f, 0.f};
    float l0 = 0.f, l1 = 0.f;   // partial denoms (this s-half): t = tg*32 + h*16 + i

    for (int kv = 0; kv < NKV; ++kv) {
        __syncthreads();   // previous iteration's LDS reads complete
        // ---- write prefetched regs -> LDS (cvt here) ----
        #pragma unroll
        for (int j = 0; j < 2; ++j) {
            const int cpair = k_c16 + 16 * j;
            float4 lo = kreg[j][0], hi = kreg[j][1];
            bf16x2 w;
            w[0] = (__bf16)lo.x; w[1] = (__bf16)hi.x;
            *(bf16x2*)(KsW + swz(k_sq + 0, cpair * 4)) = w;
            w[0] = (__bf16)lo.y; w[1] = (__bf16)hi.y;
            *(bf16x2*)(KsW + swz(k_sq + 1, cpair * 4)) = w;
            w[0] = (__bf16)lo.z; w[1] = (__bf16)hi.z;
            *(bf16x2*)(KsW + swz(k_sq + 2, cpair * 4)) = w;
            w[0] = (__bf16)lo.w; w[1] = (__bf16)hi.w;
            *(bf16x2*)(KsW + swz(k_sq + 3, cpair * 4)) = w;
        }
        #pragma unroll
        for (int p = 0; p < 4; ++p) {
            int u  = v_u0 + p;                               // chunk 0..15
            int up = (u & 8) | ((u & 3) << 1) | ((u >> 2) & 1);
            float4 f = vreg[p];
            bf16x4 hv;
            hv[0] = (__bf16)f.x; hv[1] = (__bf16)f.y;
            hv[2] = (__bf16)f.z; hv[3] = (__bf16)f.w;
            *(bf16x4*)(VsW + swz(v_c, up * 8)) = hv;
        }
        // ---- issue next tile's loads (latency hides under compute) ----
        const int s0n = (kv + 1 < NKV) ? (kv + 1) * KVBLK : 0;
        #pragma unroll
        for (int j = 0; j < 2; ++j) {
            const float* kb = (j ? kb1 : kb0) + s0n;
            kreg[j][0] = *(const float4*)(kb);
            kreg[j][1] = *(const float4*)(kb + T_LEN);
        }
        #pragma unroll
        for (int p = 0; p < 4; ++p) vreg[p] = *(const float4*)(vbase + s0n + p * 4);
        __syncthreads();   // LDS tiles ready

        // ---- S^T = K^T Q on my s-half; each K-frag feeds both t-halves ----
        f32x4 sacc[2][4];
        #pragma unroll
        for (int h = 0; h < 2; ++h)
            #pragma unroll
            for (int n = 0; n < 4; ++n) sacc[h][n] = (f32x4){0.f, 0.f, 0.f, 0.f};
        #pragma unroll
        for (int kk = 0; kk < 2; ++kk) {
            bf16x8 qf0 = *(const bf16x8*)(lds + swz(tg * 32 +  0 + i, kk * 64 + g * 16));
            bf16x8 qf1 = *(const bf16x8*)(lds + swz(tg * 32 + 16 + i, kk * 64 + g * 16));
            #pragma unroll
            for (int mt = 0; mt < 4; ++mt) {
                bf16x8 kf = *(const bf16x8*)(KsR + swz(mt * 16 + i, kk * 64 + g * 16));
                sacc[0][mt] = __builtin_amdgcn_mfma_f32_16x16x32_bf16(kf, qf0, sacc[0][mt], 0, 0, 0);
                sacc[1][mt] = __builtin_amdgcn_mfma_f32_16x16x32_bf16(kf, qf1, sacc[1][mt], 0, 0, 0);
            }
        }

        // ---- no-max softmax fused with PV; each V-frag feeds both t-halves ----
        float rs0 = 0.f, rs1 = 0.f;
        #pragma unroll
        for (int q = 0; q < 2; ++q) {
            bf16x8 pa0, pa1;
            #pragma unroll
            for (int r = 0; r < 4; ++r) {
                float a0 = exp2f(sacc[0][2 * q][r]);
                float a1 = exp2f(sacc[0][2 * q + 1][r]);
                rs0 += a0 + a1;
                pa0[r] = (__bf16)a0; pa0[4 + r] = (__bf16)a1;
                float b0 = exp2f(sacc[1][2 * q][r]);
                float b1 = exp2f(sacc[1][2 * q + 1][r]);
                rs1 += b0 + b1;
                pa1[r] = (__bf16)b0; pa1[4 + r] = (__bf16)b1;
            }
            #pragma unroll
            for (int n = 0; n < 4; ++n) {
                bf16x8 bv = *(const bf16x8*)(VsR + swz(n * 16 + i, q * 64 + g * 16));
                oacc[0][n] = __builtin_amdgcn_mfma_f32_16x16x32_bf16(pa0, bv, oacc[0][n], 0, 0, 0);
                oacc[1][n] = __builtin_amdgcn_mfma_f32_16x16x32_bf16(pa1, bv, oacc[1][n], 0, 0, 0);
            }
        }
        rs0 += __shfl_xor(rs0, 16); rs0 += __shfl_xor(rs0, 32);
        rs1 += __shfl_xor(rs1, 16); rs1 += __shfl_xor(rs1, 32);
        l0 += rs0; l1 += rs1;
    }

    // ---- merge the two s-halves (additive: no-max softmax), then epilogue ----
    __syncthreads();                       // all K/V/Q LDS reads complete
    char* mbase = lds + 32768 + tg * 8192; // [64 c][32 t] f32, swzM
    float* lbase = (float*)(lds + 65536);  // 128 partial denoms
    if (half == 1) {
        #pragma unroll
        for (int h = 0; h < 2; ++h)
            #pragma unroll
            for (int n = 0; n < 4; ++n)
                *(f32x4*)(mbase + swzM(n * 16 + i, h * 64 + g * 16)) = oacc[h][n];
        if (g == 0) { lbase[tg * 32 + i] = l0; lbase[tg * 32 + 16 + i] = l1; }
    }
    __syncthreads();
    if (half == 0) {
        #pragma unroll
        for (int h = 0; h < 2; ++h)
            #pragma unroll
            for (int n = 0; n < 4; ++n) {
                f32x4 part = *(const f32x4*)(mbase + swzM(n * 16 + i, h * 64 + g * 16));
                oacc[h][n] += part;
            }
        l0 += lbase[tg * 32 + i];
        l1 += lbase[tg * 32 + 16 + i];
        #pragma unroll
        for (int h = 0; h < 2; ++h) {
            float invl = 1.0f / (h ? l1 : l0);   // row t = tg*32 + h*16 + i
            #pragma unroll
            for (int reg = 0; reg < 4; ++reg) {
                float inv_r = __shfl(invl, g * 4 + reg);
                int t_loc = tg * 32 + h * 16 + g * 4 + reg;   // 0..127
                #pragma unroll
                for (int n = 0; n < 4; ++n) {
                    int c = n * 16 + i;
                    *(float*)(lds + swzO(c, t_loc * 4)) = oacc[h][n][reg] * inv_r;
                }
            }
        }
    }
    __syncthreads();
    #pragma unroll
    for (int it = 0; it < 4; ++it) {
        int idx = it * 512 + tid;       // 2048 chunks of 16B
        int c   = idx >> 5;             // 0..63
        int seg = idx & 31;             // 16B chunk within the 512B t-row
        float4 u = *(const float4*)(lds + swzO(c, seg * 16));
        *(float4*)(out + (size_t)(bh * 64 + c) * T_LEN + t0 + seg * 4) = u;
    }
}

extern "C" void kernel_launch(void* const* d_in, const int* in_sizes, int n_in,
                              void* d_out, int out_size, void* d_ws, size_t ws_size,
                              hipStream_t stream) {
    const float* qkv = (const float*)d_in[0];
    float* out = (float*)d_out;
    qkv_attn_kernel<<<dim3(512), dim3(512), 0, stream>>>(qkv, out);
}

// Round 13
// 135.676 us; speedup vs baseline: 2.0671x; 2.0671x over previous
//
#include <hip/hip_runtime.h>
#include <hip/hip_bf16.h>

typedef __bf16 bf16x8 __attribute__((ext_vector_type(8)));
typedef __bf16 bf16x4 __attribute__((ext_vector_type(4)));
typedef __bf16 bf16x2 __attribute__((ext_vector_type(2)));
typedef float  f32x4  __attribute__((ext_vector_type(4)));

#define T_LEN 4096
#define QBLK  128
#define KVBLK 128
#define NKV   (T_LEN / KVBLK)   // 32

// 8 waves = 4 t-groups (32 rows, R=2 halves) x 2 s-halves; 2 blocks/CU ->
// 16 waves/CU. r12 lesson: this structure + 32-reg prefetch spilled
// (WRITE_SIZE 187MB). Fix: no reg prefetch (TLP hides staging at 16 w/CU),
// Q-fragments hoisted to registers (loop-invariant, -4 ds_reads/tile).
//
// LDS map (bytes):
//   [0,     16384)  Qs : [128 t][64 c] bf16, swizzled  } [0,32768) reused as
//   [16384, 24576)  Ks0: [64 s][64 c] bf16, swizzled   } f32 Obuf in epilogue
//   [24576, 32768)  Ks1: s=64..127
//   [32768, 40960)  Vs0: [64 c][64 s-permuted] bf16    } [32768,65536) reused
//   [40960, 49152)  Vs1: s=64..127                     } as merge buf (post-loop)
//   [65536, 66048)  l-merge (128 f32)
__device__ __forceinline__ int swz(int row, int colByte) {
    return row * 128 + (colByte ^ (((row ^ (row >> 2)) & 7) << 4));
}
__device__ __forceinline__ int swzM(int row, int colByte) {   // merge buf [c][t] f32
    return row * 128 + (colByte ^ ((row & 7) << 4));
}
// f32 epilogue buffer: row = c (512B of t), XOR in 32B units
__device__ __forceinline__ int swzO(int row, int colByte) {
    return row * 512 + (colByte ^ ((row & 7) << 5));
}

// Q pre-scale: 1/8 (QK scale) x log2(e); no-max exp2 softmax (r9-verified).
#define QSCALE 0.18033688011112042f

__global__ __launch_bounds__(512, 4)
void qkv_attn_kernel(const float* __restrict__ qkv, float* __restrict__ out) {
    __shared__ __align__(16) char lds[66560];

    // T1 XCD swizzle (512 wgs = 8 XCDs x 64, bijective simple form).
    const int fid   = (blockIdx.x & 7) * 64 + (blockIdx.x >> 3);
    const int bh    = fid >> 5;     // 0..15
    const int ttile = fid & 31;     // 0..31
    const float* qp = qkv + (size_t)bh * 192 * T_LEN;
    const float* kp = qp + (size_t)64  * T_LEN;
    const float* vp = qp + (size_t)128 * T_LEN;
    const int t0 = ttile * QBLK;

    const int tid  = threadIdx.x;
    const int wave = tid >> 6, lane = tid & 63;
    const int g = lane >> 4, i = lane & 15;
    const int tg = wave >> 1, half = wave & 1;   // t-group, s-half

    // staging coordinates (loop-invariant); each thread stages one s-subtile.
    const int ssub  = tid >> 8;            // 0/1: which 64-s subtile I stage
    char* const KsW = lds + 16384 + ssub * 8192;
    char* const VsW = lds + 32768 + ssub * 8192;
    char* const KsR = lds + 16384 + half * 8192;   // compute-side (my s-half)
    char* const VsR = lds + 32768 + half * 8192;

    const int k_sq  = (tid & 15) * 4;      // s-quad within subtile
    const int k_c16 = (tid >> 4) & 15;     // cpairs k_c16, k_c16+16
    const float* kb0 = kp + (size_t)(k_c16 * 2)        * T_LEN + ssub * 64 + k_sq;
    const float* kb1 = kp + (size_t)((k_c16 + 16) * 2) * T_LEN + ssub * 64 + k_sq;
    const int v_c  = (tid >> 2) & 63;      // channel row
    const int v_u0 = (tid & 3) * 4;        // base 4-s chunk
    const float* vbase = vp + (size_t)v_c * T_LEN + ssub * 64 + v_u0 * 4;

    // ---- stage Q^T x QSCALE : [128 t][64 c] ----
    {
        const int tq  = (tid & 31) * 4;   // 0..124
        const int cp8 = tid >> 5;         // 0..15; pairs cp8, cp8+16
        #pragma unroll
        for (int hh = 0; hh < 2; ++hh) {
            const int cpair = cp8 + hh * 16;            // 0..31
            const float* base = qp + (size_t)(cpair * 2) * T_LEN + t0 + tq;
            float4 lo = *(const float4*)(base);
            float4 hi = *(const float4*)(base + T_LEN);
            bf16x2 v;
            v[0] = (__bf16)(lo.x * QSCALE); v[1] = (__bf16)(hi.x * QSCALE);
            *(bf16x2*)(lds + swz(tq + 0, cpair * 4)) = v;
            v[0] = (__bf16)(lo.y * QSCALE); v[1] = (__bf16)(hi.y * QSCALE);
            *(bf16x2*)(lds + swz(tq + 1, cpair * 4)) = v;
            v[0] = (__bf16)(lo.z * QSCALE); v[1] = (__bf16)(hi.z * QSCALE);
            *(bf16x2*)(lds + swz(tq + 2, cpair * 4)) = v;
            v[0] = (__bf16)(lo.w * QSCALE); v[1] = (__bf16)(hi.w * QSCALE);
            *(bf16x2*)(lds + swz(tq + 3, cpair * 4)) = v;
        }
    }
    __syncthreads();
    // ---- hoist my Q fragments to registers (loop-invariant) ----
    bf16x8 qreg[2][2];   // [t-half][kk]
    #pragma unroll
    for (int h = 0; h < 2; ++h)
        #pragma unroll
        for (int kk = 0; kk < 2; ++kk)
            qreg[h][kk] = *(const bf16x8*)(lds + swz(tg * 32 + h * 16 + i, kk * 64 + g * 16));

    f32x4 oacc[2][4];
    #pragma unroll
    for (int h = 0; h < 2; ++h)
        #pragma unroll
        for (int n = 0; n < 4; ++n) oacc[h][n] = (f32x4){0.f, 0.f, 0.f, 0.f};
    float l0 = 0.f, l1 = 0.f;   // partial denoms (this s-half): t = tg*32 + h*16 + i

    for (int kv = 0; kv < NKV; ++kv) {
        const int s0 = kv * KVBLK;
        __syncthreads();   // previous iteration's LDS reads complete
        // ---- stage K^T + V directly (no reg prefetch: TLP hides latency) ----
        #pragma unroll
        for (int j = 0; j < 2; ++j) {
            const int cpair = k_c16 + 16 * j;
            const float* kb = (j ? kb1 : kb0) + s0;
            float4 lo = *(const float4*)(kb);
            float4 hi = *(const float4*)(kb + T_LEN);
            bf16x2 w;
            w[0] = (__bf16)lo.x; w[1] = (__bf16)hi.x;
            *(bf16x2*)(KsW + swz(k_sq + 0, cpair * 4)) = w;
            w[0] = (__bf16)lo.y; w[1] = (__bf16)hi.y;
            *(bf16x2*)(KsW + swz(k_sq + 1, cpair * 4)) = w;
            w[0] = (__bf16)lo.z; w[1] = (__bf16)hi.z;
            *(bf16x2*)(KsW + swz(k_sq + 2, cpair * 4)) = w;
            w[0] = (__bf16)lo.w; w[1] = (__bf16)hi.w;
            *(bf16x2*)(KsW + swz(k_sq + 3, cpair * 4)) = w;
        }
        #pragma unroll
        for (int p = 0; p < 4; ++p) {
            int u  = v_u0 + p;                               // chunk 0..15
            int up = (u & 8) | ((u & 3) << 1) | ((u >> 2) & 1);
            float4 f = *(const float4*)(vbase + s0 + p * 4);
            bf16x4 hv;
            hv[0] = (__bf16)f.x; hv[1] = (__bf16)f.y;
            hv[2] = (__bf16)f.z; hv[3] = (__bf16)f.w;
            *(bf16x4*)(VsW + swz(v_c, up * 8)) = hv;
        }
        __syncthreads();   // LDS tiles ready

        // ---- S^T = K^T Q on my s-half; each K-frag feeds both t-halves ----
        f32x4 sacc[2][4];
        #pragma unroll
        for (int h = 0; h < 2; ++h)
            #pragma unroll
            for (int n = 0; n < 4; ++n) sacc[h][n] = (f32x4){0.f, 0.f, 0.f, 0.f};
        #pragma unroll
        for (int kk = 0; kk < 2; ++kk)
            #pragma unroll
            for (int mt = 0; mt < 4; ++mt) {
                bf16x8 kf = *(const bf16x8*)(KsR + swz(mt * 16 + i, kk * 64 + g * 16));
                sacc[0][mt] = __builtin_amdgcn_mfma_f32_16x16x32_bf16(kf, qreg[0][kk], sacc[0][mt], 0, 0, 0);
                sacc[1][mt] = __builtin_amdgcn_mfma_f32_16x16x32_bf16(kf, qreg[1][kk], sacc[1][mt], 0, 0, 0);
            }

        // ---- no-max softmax fused with PV; each V-frag feeds both t-halves ----
        float rs0 = 0.f, rs1 = 0.f;
        #pragma unroll
        for (int q = 0; q < 2; ++q) {
            bf16x8 pa0, pa1;
            #pragma unroll
            for (int r = 0; r < 4; ++r) {
                float a0 = exp2f(sacc[0][2 * q][r]);
                float a1 = exp2f(sacc[0][2 * q + 1][r]);
                rs0 += a0 + a1;
                pa0[r] = (__bf16)a0; pa0[4 + r] = (__bf16)a1;
                float b0 = exp2f(sacc[1][2 * q][r]);
                float b1 = exp2f(sacc[1][2 * q + 1][r]);
                rs1 += b0 + b1;
                pa1[r] = (__bf16)b0; pa1[4 + r] = (__bf16)b1;
            }
            #pragma unroll
            for (int n = 0; n < 4; ++n) {
                bf16x8 bv = *(const bf16x8*)(VsR + swz(n * 16 + i, q * 64 + g * 16));
                oacc[0][n] = __builtin_amdgcn_mfma_f32_16x16x32_bf16(pa0, bv, oacc[0][n], 0, 0, 0);
                oacc[1][n] = __builtin_amdgcn_mfma_f32_16x16x32_bf16(pa1, bv, oacc[1][n], 0, 0, 0);
            }
        }
        rs0 += __shfl_xor(rs0, 16); rs0 += __shfl_xor(rs0, 32);
        rs1 += __shfl_xor(rs1, 16); rs1 += __shfl_xor(rs1, 32);
        l0 += rs0; l1 += rs1;
    }

    // ---- merge the two s-halves (additive: no-max softmax), then epilogue ----
    __syncthreads();                       // all K/V LDS reads complete
    char* mbase = lds + 32768 + tg * 8192; // [64 c][32 t] f32, swzM
    float* lbase = (float*)(lds + 65536);  // 128 partial denoms
    if (half == 1) {
        #pragma unroll
        for (int h = 0; h < 2; ++h)
            #pragma unroll
            for (int n = 0; n < 4; ++n)
                *(f32x4*)(mbase + swzM(n * 16 + i, h * 64 + g * 16)) = oacc[h][n];
        if (g == 0) { lbase[tg * 32 + i] = l0; lbase[tg * 32 + 16 + i] = l1; }
    }
    __syncthreads();
    if (half == 0) {
        #pragma unroll
        for (int h = 0; h < 2; ++h)
            #pragma unroll
            for (int n = 0; n < 4; ++n) {
                f32x4 part = *(const f32x4*)(mbase + swzM(n * 16 + i, h * 64 + g * 16));
                oacc[h][n] += part;
            }
        l0 += lbase[tg * 32 + i];
        l1 += lbase[tg * 32 + 16 + i];
        #pragma unroll
        for (int h = 0; h < 2; ++h) {
            float invl = 1.0f / (h ? l1 : l0);   // row t = tg*32 + h*16 + i
            #pragma unroll
            for (int reg = 0; reg < 4; ++reg) {
                float inv_r = __shfl(invl, g * 4 + reg);
                int t_loc = tg * 32 + h * 16 + g * 4 + reg;   // 0..127
                #pragma unroll
                for (int n = 0; n < 4; ++n) {
                    int c = n * 16 + i;
                    *(float*)(lds + swzO(c, t_loc * 4)) = oacc[h][n][reg] * inv_r;
                }
            }
        }
    }
    __syncthreads();
    #pragma unroll
    for (int it = 0; it < 4; ++it) {
        int idx = it * 512 + tid;       // 2048 chunks of 16B
        int c   = idx >> 5;             // 0..63
        int seg = idx & 31;             // 16B chunk within the 512B t-row
        float4 u = *(const float4*)(lds + swzO(c, seg * 16));
        *(float4*)(out + (size_t)(bh * 64 + c) * T_LEN + t0 + seg * 4) = u;
    }
}

extern "C" void kernel_launch(void* const* d_in, const int* in_sizes, int n_in,
                              void* d_out, int out_size, void* d_ws, size_t ws_size,
                              hipStream_t stream) {
    const float* qkv = (const float*)d_in[0];
    float* out = (float*)d_out;
    qkv_attn_kernel<<<dim3(512), dim3(512), 0, stream>>>(qkv, out);
}

// Round 14
// 107.256 us; speedup vs baseline: 2.6149x; 1.2650x over previous
//
#include <hip/hip_runtime.h>
#include <hip/hip_bf16.h>

typedef __bf16 bf16x8 __attribute__((ext_vector_type(8)));
typedef __bf16 bf16x4 __attribute__((ext_vector_type(4)));
typedef __bf16 bf16x2 __attribute__((ext_vector_type(2)));
typedef float  f32x4  __attribute__((ext_vector_type(4)));

#define T_LEN 4096
#define QBLK  128
#define KVBLK 64
#define NKV   (T_LEN / KVBLK)   // 64

// r13 lesson: all serial-staging variants plateau at ~130us; the per-tile
// {barrier, stage, barrier, compute} chain is the limiter. This round:
// KVBLK=64 + K/V DOUBLE BUFFER -> one barrier/tile, staging loads issued
// before compute (latency hidden), ds_writes after compute (so MFMA lgkm
// waits never drain them). 8 waves = 4 t-groups x 2 s-halves (32s each).
//
// LDS map (bytes):
//   [0,     16384)  Qs : [128 t][64 c] bf16, swizzled } [0,32768) reused as
//   [16384, 32768)  Ks buf0/buf1: [64 s][64 c] bf16   } f32 Obuf in epilogue
//   [32768, 49152)  Vs buf0/buf1: [64 c][64 s-perm]   } [32768,65536) reused
//   [65536, 66048)  l-merge (128 f32)                 } as merge buf post-loop
__device__ __forceinline__ int swz(int row, int colByte) {
    return row * 128 + (colByte ^ (((row ^ (row >> 2)) & 7) << 4));
}
__device__ __forceinline__ int swzM(int row, int colByte) {   // merge buf [c][t] f32
    return row * 128 + (colByte ^ ((row & 7) << 4));
}
__device__ __forceinline__ int swzO(int row, int colByte) {   // epilogue f32 [c][128t]
    return row * 512 + (colByte ^ ((row & 7) << 5));
}

// Q pre-scale: 1/8 (QK scale) x log2(e); no-max exp2 softmax (r9-verified).
#define QSCALE 0.18033688011112042f

// Bare v_exp_f32: our args are |x| <~ 12, so OCML exp2f's denormal-range
// fixup (~4 extra VALU ops per call) is dead weight.
#if __has_builtin(__builtin_amdgcn_exp2f)
#define EXP2(x) __builtin_amdgcn_exp2f(x)
#else
__device__ __forceinline__ float EXP2(float x) {
    float r; asm("v_exp_f32 %0, %1" : "=v"(r) : "v"(x)); return r;
}
#endif

__global__ __launch_bounds__(512, 4)
void qkv_attn_kernel(const float* __restrict__ qkv, float* __restrict__ out) {
    __shared__ __align__(16) char lds[66560];

    // T1 XCD swizzle (512 wgs = 8 XCDs x 64, bijective simple form).
    const int fid   = (blockIdx.x & 7) * 64 + (blockIdx.x >> 3);
    const int bh    = fid >> 5;     // 0..15
    const int ttile = fid & 31;     // 0..31
    const float* qp = qkv + (size_t)bh * 192 * T_LEN;
    const float* kp = qp + (size_t)64  * T_LEN;
    const float* vp = qp + (size_t)128 * T_LEN;
    const int t0 = ttile * QBLK;

    const int tid  = threadIdx.x;
    const int wave = tid >> 6, lane = tid & 63;
    const int g = lane >> 4, i = lane & 15;
    const int tg = wave >> 1, half = wave & 1;   // t-group, s-half (32s each)

    // staging coordinates (loop-invariant): whole block stages the 64-s tile
    const int k_c  = tid >> 4;             // cpair 0..31 -> channels 2c, 2c+1
    const int k_sq = (tid & 15) * 4;       // s-quad
    const float* kbase = kp + (size_t)(k_c * 2) * T_LEN + k_sq;
    const int v_c  = tid >> 3;             // channel row 0..63
    const int v_u0 = (tid & 7) * 2;        // 2 chunks of 4 s
    const float* vbase = vp + (size_t)v_c * T_LEN + v_u0 * 4;

    // ---- stage Q^T x QSCALE : [128 t][64 c] ----
    {
        const int tq  = (tid & 31) * 4;   // 0..124
        const int cp8 = tid >> 5;         // 0..15; pairs cp8, cp8+16
        #pragma unroll
        for (int hh = 0; hh < 2; ++hh) {
            const int cpair = cp8 + hh * 16;            // 0..31
            const float* base = qp + (size_t)(cpair * 2) * T_LEN + t0 + tq;
            float4 lo = *(const float4*)(base);
            float4 hi = *(const float4*)(base + T_LEN);
            bf16x2 v;
            v[0] = (__bf16)(lo.x * QSCALE); v[1] = (__bf16)(hi.x * QSCALE);
            *(bf16x2*)(lds + swz(tq + 0, cpair * 4)) = v;
            v[0] = (__bf16)(lo.y * QSCALE); v[1] = (__bf16)(hi.y * QSCALE);
            *(bf16x2*)(lds + swz(tq + 1, cpair * 4)) = v;
            v[0] = (__bf16)(lo.z * QSCALE); v[1] = (__bf16)(hi.z * QSCALE);
            *(bf16x2*)(lds + swz(tq + 2, cpair * 4)) = v;
            v[0] = (__bf16)(lo.w * QSCALE); v[1] = (__bf16)(hi.w * QSCALE);
            *(bf16x2*)(lds + swz(tq + 3, cpair * 4)) = v;
        }
    }
    // ---- prologue: stage tile 0 into buf0 directly ----
    {
        float4 lo = *(const float4*)(kbase);
        float4 hi = *(const float4*)(kbase + T_LEN);
        bf16x2 w;
        char* KsW = lds + 16384;
        w[0] = (__bf16)lo.x; w[1] = (__bf16)hi.x; *(bf16x2*)(KsW + swz(k_sq + 0, k_c * 4)) = w;
        w[0] = (__bf16)lo.y; w[1] = (__bf16)hi.y; *(bf16x2*)(KsW + swz(k_sq + 1, k_c * 4)) = w;
        w[0] = (__bf16)lo.z; w[1] = (__bf16)hi.z; *(bf16x2*)(KsW + swz(k_sq + 2, k_c * 4)) = w;
        w[0] = (__bf16)lo.w; w[1] = (__bf16)hi.w; *(bf16x2*)(KsW + swz(k_sq + 3, k_c * 4)) = w;
        char* VsW = lds + 32768;
        #pragma unroll
        for (int p = 0; p < 2; ++p) {
            int u  = v_u0 + p;
            int up = (u & 8) | ((u & 3) << 1) | ((u >> 2) & 1);
            float4 f = *(const float4*)(vbase + p * 4);
            bf16x4 hv;
            hv[0] = (__bf16)f.x; hv[1] = (__bf16)f.y;
            hv[2] = (__bf16)f.z; hv[3] = (__bf16)f.w;
            *(bf16x4*)(VsW + swz(v_c, up * 8)) = hv;
        }
    }
    __syncthreads();
    // ---- hoist my Q fragments to registers (loop-invariant) ----
    bf16x8 qreg[2][2];   // [t-half][kk]
    #pragma unroll
    for (int h = 0; h < 2; ++h)
        #pragma unroll
        for (int kk = 0; kk < 2; ++kk)
            qreg[h][kk] = *(const bf16x8*)(lds + swz(tg * 32 + h * 16 + i, kk * 64 + g * 16));

    f32x4 oacc[2][4];
    #pragma unroll
    for (int h = 0; h < 2; ++h)
        #pragma unroll
        for (int n = 0; n < 4; ++n) oacc[h][n] = (f32x4){0.f, 0.f, 0.f, 0.f};
    float l0 = 0.f, l1 = 0.f;   // partial denoms (my s-half): t = tg*32 + h*16 + i

    for (int kv = 0; kv < NKV; ++kv) {
        // ---- issue next tile's global loads (latency hides under compute) ----
        const int s0n = (kv + 1 < NKV) ? (kv + 1) * KVBLK : 0;
        float4 klo = *(const float4*)(kbase + s0n);
        float4 khi = *(const float4*)(kbase + T_LEN + s0n);
        float4 vl0 = *(const float4*)(vbase + s0n);
        float4 vl1 = *(const float4*)(vbase + s0n + 4);

        // ---- compute from buf[kv&1] ----
        char* KsR = lds + 16384 + (kv & 1) * 8192;
        char* VsR = lds + 32768 + (kv & 1) * 8192;
        f32x4 sacc[2][2];
        #pragma unroll
        for (int h = 0; h < 2; ++h)
            #pragma unroll
            for (int mt = 0; mt < 2; ++mt) sacc[h][mt] = (f32x4){0.f, 0.f, 0.f, 0.f};
        #pragma unroll
        for (int kk = 0; kk < 2; ++kk)
            #pragma unroll
            for (int mt = 0; mt < 2; ++mt) {
                bf16x8 kf = *(const bf16x8*)(KsR + swz(half * 32 + mt * 16 + i, kk * 64 + g * 16));
                sacc[0][mt] = __builtin_amdgcn_mfma_f32_16x16x32_bf16(kf, qreg[0][kk], sacc[0][mt], 0, 0, 0);
                sacc[1][mt] = __builtin_amdgcn_mfma_f32_16x16x32_bf16(kf, qreg[1][kk], sacc[1][mt], 0, 0, 0);
            }
        float rs0 = 0.f, rs1 = 0.f;
        bf16x8 pa0, pa1;
        #pragma unroll
        for (int r = 0; r < 4; ++r) {
            float a0 = EXP2(sacc[0][0][r]);
            float a1 = EXP2(sacc[0][1][r]);
            rs0 += a0 + a1;
            pa0[r] = (__bf16)a0; pa0[4 + r] = (__bf16)a1;
            float b0 = EXP2(sacc[1][0][r]);
            float b1 = EXP2(sacc[1][1][r]);
            rs1 += b0 + b1;
            pa1[r] = (__bf16)b0; pa1[4 + r] = (__bf16)b1;
        }
        #pragma unroll
        for (int n = 0; n < 4; ++n) {
            bf16x8 bv = *(const bf16x8*)(VsR + swz(n * 16 + i, half * 64 + g * 16));
            oacc[0][n] = __builtin_amdgcn_mfma_f32_16x16x32_bf16(pa0, bv, oacc[0][n], 0, 0, 0);
            oacc[1][n] = __builtin_amdgcn_mfma_f32_16x16x32_bf16(pa1, bv, oacc[1][n], 0, 0, 0);
        }
        rs0 += __shfl_xor(rs0, 16); rs0 += __shfl_xor(rs0, 32);
        rs1 += __shfl_xor(rs1, 16); rs1 += __shfl_xor(rs1, 32);
        l0 += rs0; l1 += rs1;

        // ---- cvt + write next tile into buf[(kv+1)&1] (after compute reads) ----
        if (kv + 1 < NKV) {
            char* KsW = lds + 16384 + ((kv + 1) & 1) * 8192;
            char* VsW = lds + 32768 + ((kv + 1) & 1) * 8192;
            bf16x2 w;
            w[0] = (__bf16)klo.x; w[1] = (__bf16)khi.x; *(bf16x2*)(KsW + swz(k_sq + 0, k_c * 4)) = w;
            w[0] = (__bf16)klo.y; w[1] = (__bf16)khi.y; *(bf16x2*)(KsW + swz(k_sq + 1, k_c * 4)) = w;
            w[0] = (__bf16)klo.z; w[1] = (__bf16)khi.z; *(bf16x2*)(KsW + swz(k_sq + 2, k_c * 4)) = w;
            w[0] = (__bf16)klo.w; w[1] = (__bf16)khi.w; *(bf16x2*)(KsW + swz(k_sq + 3, k_c * 4)) = w;
            #pragma unroll
            for (int p = 0; p < 2; ++p) {
                int u  = v_u0 + p;
                int up = (u & 8) | ((u & 3) << 1) | ((u >> 2) & 1);
                float4 f = p ? vl1 : vl0;
                bf16x4 hv;
                hv[0] = (__bf16)f.x; hv[1] = (__bf16)f.y;
                hv[2] = (__bf16)f.z; hv[3] = (__bf16)f.w;
                *(bf16x4*)(VsW + swz(v_c, up * 8)) = hv;
            }
        }
        __syncthreads();   // writes visible; also fences reads before next overwrite
    }

    // ---- merge the two s-halves (additive: no-max softmax), then epilogue ----
    char* mbase = lds + 32768 + tg * 8192; // [64 c][32 t] f32, swzM (post-loop reuse)
    float* lbase = (float*)(lds + 65536);  // 128 partial denoms
    if (half == 1) {
        #pragma unroll
        for (int h = 0; h < 2; ++h)
            #pragma unroll
            for (int n = 0; n < 4; ++n)
                *(f32x4*)(mbase + swzM(n * 16 + i, h * 64 + g * 16)) = oacc[h][n];
        if (g == 0) { lbase[tg * 32 + i] = l0; lbase[tg * 32 + 16 + i] = l1; }
    }
    __syncthreads();
    if (half == 0) {
        #pragma unroll
        for (int h = 0; h < 2; ++h)
            #pragma unroll
            for (int n = 0; n < 4; ++n) {
                f32x4 part = *(const f32x4*)(mbase + swzM(n * 16 + i, h * 64 + g * 16));
                oacc[h][n] += part;
            }
        l0 += lbase[tg * 32 + i];
        l1 += lbase[tg * 32 + 16 + i];
        #pragma unroll
        for (int h = 0; h < 2; ++h) {
            float invl = 1.0f / (h ? l1 : l0);   // row t = tg*32 + h*16 + i
            #pragma unroll
            for (int reg = 0; reg < 4; ++reg) {
                float inv_r = __shfl(invl, g * 4 + reg);
                int t_loc = tg * 32 + h * 16 + g * 4 + reg;   // 0..127
                #pragma unroll
                for (int n = 0; n < 4; ++n) {
                    int c = n * 16 + i;
                    *(float*)(lds + swzO(c, t_loc * 4)) = oacc[h][n][reg] * inv_r;
                }
            }
        }
    }
    __syncthreads();
    #pragma unroll
    for (int it = 0; it < 4; ++it) {
        int idx = it * 512 + tid;       // 2048 chunks of 16B
        int c   = idx >> 5;             // 0..63
        int seg = idx & 31;             // 16B chunk within the 512B t-row
        float4 u = *(const float4*)(lds + swzO(c, seg * 16));
        *(float4*)(out + (size_t)(bh * 64 + c) * T_LEN + t0 + seg * 4) = u;
    }
}

extern "C" void kernel_launch(void* const* d_in, const int* in_sizes, int n_in,
                              void* d_out, int out_size, void* d_ws, size_t ws_size,
                              hipStream_t stream) {
    const float* qkv = (const float*)d_in[0];
    float* out = (float*)d_out;
    qkv_attn_kernel<<<dim3(512), dim3(512), 0, stream>>>(qkv, out);
}

// Round 15
// 96.574 us; speedup vs baseline: 2.9041x; 1.1106x over previous
//
#include <hip/hip_runtime.h>
#include <hip/hip_bf16.h>

typedef __bf16 bf16x8 __attribute__((ext_vector_type(8)));
typedef __bf16 bf16x4 __attribute__((ext_vector_type(4)));
typedef __bf16 bf16x2 __attribute__((ext_vector_type(2)));
typedef float  f32x4  __attribute__((ext_vector_type(4)));

#define T_LEN 4096
#define QBLK  128
#define KVBLK 64
#define NKV   (T_LEN / KVBLK)   // 64

__device__ __forceinline__ int swz(int row, int colByte) {
    return row * 128 + (colByte ^ (((row ^ (row >> 2)) & 7) << 4));
}
__device__ __forceinline__ int swzM(int row, int colByte) {   // merge buf [c][t] f32
    return row * 128 + (colByte ^ ((row & 7) << 4));
}
__device__ __forceinline__ int swzO(int row, int colByte) {   // epilogue f32 [c][128t]
    return row * 512 + (colByte ^ ((row & 7) << 5));
}

// Q pre-scale: 1/8 (QK scale) x log2(e); no-max exp2 softmax (r9-verified).
#define QSCALE 0.18033688011112042f

#if __has_builtin(__builtin_amdgcn_exp2f)
#define EXP2(x) __builtin_amdgcn_exp2f(x)
#else
__device__ __forceinline__ float EXP2(float x) {
    float r; asm("v_exp_f32 %0, %1" : "=v"(r) : "v"(x)); return r;
}
#endif

// async global->LDS, 16B/lane; LDS dest = wave-uniform base + lane*16.
__device__ __forceinline__ void glds16(const void* g, void* l) {
    __builtin_amdgcn_global_load_lds(
        (const __attribute__((address_space(1))) void*)g,
        (__attribute__((address_space(3))) void*)l, 16, 0, 0);
}

// ---------------- prepass: K,V -> bf16 swizzled LDS images in d_ws ----------
// Per (bh, tile): 8192B K image ([64 s][64 c] bf16, swz) and 8192B V image
// ([64 c][64 s-chunk-permuted] bf16, swz) — byte-identical to what r14's
// in-loop staging produced, so the main kernel's reads are unchanged.
__global__ __launch_bounds__(256)
void qkv_prepass(const float* __restrict__ qkv, char* __restrict__ kpan,
                 char* __restrict__ vpan) {
    const int tile = blockIdx.x;    // 0..63
    const int bh   = blockIdx.y;    // 0..15
    const float* kp = qkv + ((size_t)bh * 192 + 64)  * T_LEN + tile * 64;
    const float* vp = qkv + ((size_t)bh * 192 + 128) * T_LEN + tile * 64;
    char* kout = kpan + (size_t)(bh * 64 + tile) * 8192;
    char* vout = vpan + (size_t)(bh * 64 + tile) * 8192;

    const int t  = threadIdx.x;
    const int s  = t & 63;          // K: s_local (lanes consecutive -> coalesced)
    const int o4 = t >> 6;          // 0..3
    #pragma unroll
    for (int oo = 0; oo < 2; ++oo) {
        const int oct = o4 + oo * 4;                 // c-octet 0..7
        bf16x8 v;
        #pragma unroll
        for (int j = 0; j < 8; ++j)
            v[j] = (__bf16)kp[(size_t)(oct * 8 + j) * T_LEN + s];
        *(bf16x8*)(kout + swz(s, oct * 16)) = v;
    }
    const int c = t & 63;           // V: channel row
    #pragma unroll
    for (int p = 0; p < 4; ++p) {
        const int u = o4 * 4 + p;                    // s-chunk 0..15
        float4 f = *(const float4*)(vp + (size_t)c * T_LEN + u * 4);
        const int up = (u & 8) | ((u & 3) << 1) | ((u >> 2) & 1);
        bf16x4 hv;
        hv[0] = (__bf16)f.x; hv[1] = (__bf16)f.y;
        hv[2] = (__bf16)f.z; hv[3] = (__bf16)f.w;
        *(bf16x4*)(vout + swz(c, up * 8)) = hv;
    }
}

// ---------------- main kernel: glds staging (zero staging VALU/ds_write) ----
// LDS map: [0,16K) Qs | [16K,32K) Ks dbuf | [32K,48K) Vs dbuf | [49152] l-merge.
// Merge buf reuses [16K,48K) post-loop; epilogue Obuf reuses [0,32K) after an
// extra barrier (mbase for tg0/1 lives inside the Obuf range).
__global__ __launch_bounds__(512, 4)
void qkv_attn_glds(const float* __restrict__ qkv, float* __restrict__ out,
                   const char* __restrict__ kpan, const char* __restrict__ vpan) {
    __shared__ __align__(16) char lds[49664];

    const int fid   = (blockIdx.x & 7) * 64 + (blockIdx.x >> 3);   // T1 swizzle
    const int bh    = fid >> 5;
    const int ttile = fid & 31;
    const float* qp = qkv + (size_t)bh * 192 * T_LEN;
    const char* kpb = kpan + (size_t)bh * 64 * 8192;
    const char* vpb = vpan + (size_t)bh * 64 * 8192;
    const int t0 = ttile * QBLK;

    const int tid  = threadIdx.x;
    const int wave = tid >> 6, lane = tid & 63;
    const int g = lane >> 4, i = lane & 15;
    const int tg = wave >> 1, half = wave & 1;   // t-group, s-half (32s each)

    // ---- prologue: async-stage tile 0 into buf0 (overlaps Q staging) ----
    glds16(kpb + tid * 16, lds + 16384 + wave * 1024);
    glds16(vpb + tid * 16, lds + 32768 + wave * 1024);

    // ---- stage Q^T x QSCALE : [128 t][64 c] ----
    {
        const int tq  = (tid & 31) * 4;
        const int cp8 = tid >> 5;
        #pragma unroll
        for (int hh = 0; hh < 2; ++hh) {
            const int cpair = cp8 + hh * 16;
            const float* base = qp + (size_t)(cpair * 2) * T_LEN + t0 + tq;
            float4 lo = *(const float4*)(base);
            float4 hi = *(const float4*)(base + T_LEN);
            bf16x2 v;
            v[0] = (__bf16)(lo.x * QSCALE); v[1] = (__bf16)(hi.x * QSCALE);
            *(bf16x2*)(lds + swz(tq + 0, cpair * 4)) = v;
            v[0] = (__bf16)(lo.y * QSCALE); v[1] = (__bf16)(hi.y * QSCALE);
            *(bf16x2*)(lds + swz(tq + 1, cpair * 4)) = v;
            v[0] = (__bf16)(lo.z * QSCALE); v[1] = (__bf16)(hi.z * QSCALE);
            *(bf16x2*)(lds + swz(tq + 2, cpair * 4)) = v;
            v[0] = (__bf16)(lo.w * QSCALE); v[1] = (__bf16)(hi.w * QSCALE);
            *(bf16x2*)(lds + swz(tq + 3, cpair * 4)) = v;
        }
    }
    __syncthreads();   // Q staged + tile-0 glds drained
    bf16x8 qreg[2][2];   // [t-half][kk], loop-invariant
    #pragma unroll
    for (int h = 0; h < 2; ++h)
        #pragma unroll
        for (int kk = 0; kk < 2; ++kk)
            qreg[h][kk] = *(const bf16x8*)(lds + swz(tg * 32 + h * 16 + i, kk * 64 + g * 16));

    f32x4 oacc[2][4];
    #pragma unroll
    for (int h = 0; h < 2; ++h)
        #pragma unroll
        for (int n = 0; n < 4; ++n) oacc[h][n] = (f32x4){0.f, 0.f, 0.f, 0.f};
    float l0 = 0.f, l1 = 0.f;

    for (int kv = 0; kv < NKV; ++kv) {
        // ---- async-issue next tile (latency hides under compute) ----
        if (kv + 1 < NKV) {
            const int b = (kv + 1) & 1;
            glds16(kpb + (size_t)(kv + 1) * 8192 + tid * 16,
                   lds + 16384 + b * 8192 + wave * 1024);
            glds16(vpb + (size_t)(kv + 1) * 8192 + tid * 16,
                   lds + 32768 + b * 8192 + wave * 1024);
        }
        // ---- compute from buf[kv&1] (r14-verbatim) ----
        char* KsR = lds + 16384 + (kv & 1) * 8192;
        char* VsR = lds + 32768 + (kv & 1) * 8192;
        f32x4 sacc[2][2];
        #pragma unroll
        for (int h = 0; h < 2; ++h)
            #pragma unroll
            for (int mt = 0; mt < 2; ++mt) sacc[h][mt] = (f32x4){0.f, 0.f, 0.f, 0.f};
        #pragma unroll
        for (int kk = 0; kk < 2; ++kk)
            #pragma unroll
            for (int mt = 0; mt < 2; ++mt) {
                bf16x8 kf = *(const bf16x8*)(KsR + swz(half * 32 + mt * 16 + i, kk * 64 + g * 16));
                sacc[0][mt] = __builtin_amdgcn_mfma_f32_16x16x32_bf16(kf, qreg[0][kk], sacc[0][mt], 0, 0, 0);
                sacc[1][mt] = __builtin_amdgcn_mfma_f32_16x16x32_bf16(kf, qreg[1][kk], sacc[1][mt], 0, 0, 0);
            }
        float rs0 = 0.f, rs1 = 0.f;
        bf16x8 pa0, pa1;
        #pragma unroll
        for (int r = 0; r < 4; ++r) {
            float a0 = EXP2(sacc[0][0][r]);
            float a1 = EXP2(sacc[0][1][r]);
            rs0 += a0 + a1;
            pa0[r] = (__bf16)a0; pa0[4 + r] = (__bf16)a1;
            float b0 = EXP2(sacc[1][0][r]);
            float b1 = EXP2(sacc[1][1][r]);
            rs1 += b0 + b1;
            pa1[r] = (__bf16)b0; pa1[4 + r] = (__bf16)b1;
        }
        #pragma unroll
        for (int n = 0; n < 4; ++n) {
            bf16x8 bv = *(const bf16x8*)(VsR + swz(n * 16 + i, half * 64 + g * 16));
            oacc[0][n] = __builtin_amdgcn_mfma_f32_16x16x32_bf16(pa0, bv, oacc[0][n], 0, 0, 0);
            oacc[1][n] = __builtin_amdgcn_mfma_f32_16x16x32_bf16(pa1, bv, oacc[1][n], 0, 0, 0);
        }
        rs0 += __shfl_xor(rs0, 16); rs0 += __shfl_xor(rs0, 32);
        rs1 += __shfl_xor(rs1, 16); rs1 += __shfl_xor(rs1, 32);
        l0 += rs0; l1 += rs1;
        __syncthreads();   // next buf ready (drains glds), reads fenced
    }

    // ---- merge s-halves (additive), then epilogue ----
    char* mbase = lds + 16384 + tg * 8192;   // [64 c][32 t] f32, swzM
    float* lbase = (float*)(lds + 49152);    // 128 partial denoms
    if (half == 1) {
        #pragma unroll
        for (int h = 0; h < 2; ++h)
            #pragma unroll
            for (int n = 0; n < 4; ++n)
                *(f32x4*)(mbase + swzM(n * 16 + i, h * 64 + g * 16)) = oacc[h][n];
        if (g == 0) { lbase[tg * 32 + i] = l0; lbase[tg * 32 + 16 + i] = l1; }
    }
    __syncthreads();
    if (half == 0) {
        #pragma unroll
        for (int h = 0; h < 2; ++h)
            #pragma unroll
            for (int n = 0; n < 4; ++n)
                oacc[h][n] += *(const f32x4*)(mbase + swzM(n * 16 + i, h * 64 + g * 16));
        l0 += lbase[tg * 32 + i];
        l1 += lbase[tg * 32 + 16 + i];
    }
    __syncthreads();   // mbase reads done before Obuf overwrites [0,32K)
    if (half == 0) {
        #pragma unroll
        for (int h = 0; h < 2; ++h) {
            float invl = 1.0f / (h ? l1 : l0);
            #pragma unroll
            for (int reg = 0; reg < 4; ++reg) {
                float inv_r = __shfl(invl, g * 4 + reg);
                int t_loc = tg * 32 + h * 16 + g * 4 + reg;
                #pragma unroll
                for (int n = 0; n < 4; ++n) {
                    int c = n * 16 + i;
                    *(float*)(lds + swzO(c, t_loc * 4)) = oacc[h][n][reg] * inv_r;
                }
            }
        }
    }
    __syncthreads();
    #pragma unroll
    for (int it = 0; it < 4; ++it) {
        int idx = it * 512 + tid;
        int c   = idx >> 5;
        int seg = idx & 31;
        float4 u = *(const float4*)(lds + swzO(c, seg * 16));
        *(float4*)(out + (size_t)(bh * 64 + c) * T_LEN + t0 + seg * 4) = u;
    }
}

// ---------------- fallback (r14 kernel, used when ws_size too small) --------
__global__ __launch_bounds__(512, 4)
void qkv_attn_fb(const float* __restrict__ qkv, float* __restrict__ out) {
    __shared__ __align__(16) char lds[66560];
    const int fid   = (blockIdx.x & 7) * 64 + (blockIdx.x >> 3);
    const int bh    = fid >> 5;
    const int ttile = fid & 31;
    const float* qp = qkv + (size_t)bh * 192 * T_LEN;
    const float* kp = qp + (size_t)64  * T_LEN;
    const float* vp = qp + (size_t)128 * T_LEN;
    const int t0 = ttile * QBLK;
    const int tid  = threadIdx.x;
    const int wave = tid >> 6, lane = tid & 63;
    const int g = lane >> 4, i = lane & 15;
    const int tg = wave >> 1, half = wave & 1;
    const int k_c  = tid >> 4;
    const int k_sq = (tid & 15) * 4;
    const float* kbase = kp + (size_t)(k_c * 2) * T_LEN + k_sq;
    const int v_c  = tid >> 3;
    const int v_u0 = (tid & 7) * 2;
    const float* vbase = vp + (size_t)v_c * T_LEN + v_u0 * 4;
    {
        const int tq  = (tid & 31) * 4;
        const int cp8 = tid >> 5;
        #pragma unroll
        for (int hh = 0; hh < 2; ++hh) {
            const int cpair = cp8 + hh * 16;
            const float* base = qp + (size_t)(cpair * 2) * T_LEN + t0 + tq;
            float4 lo = *(const float4*)(base);
            float4 hi = *(const float4*)(base + T_LEN);
            bf16x2 v;
            v[0] = (__bf16)(lo.x * QSCALE); v[1] = (__bf16)(hi.x * QSCALE);
            *(bf16x2*)(lds + swz(tq + 0, cpair * 4)) = v;
            v[0] = (__bf16)(lo.y * QSCALE); v[1] = (__bf16)(hi.y * QSCALE);
            *(bf16x2*)(lds + swz(tq + 1, cpair * 4)) = v;
            v[0] = (__bf16)(lo.z * QSCALE); v[1] = (__bf16)(hi.z * QSCALE);
            *(bf16x2*)(lds + swz(tq + 2, cpair * 4)) = v;
            v[0] = (__bf16)(lo.w * QSCALE); v[1] = (__bf16)(hi.w * QSCALE);
            *(bf16x2*)(lds + swz(tq + 3, cpair * 4)) = v;
        }
    }
    {
        float4 lo = *(const float4*)(kbase);
        float4 hi = *(const float4*)(kbase + T_LEN);
        bf16x2 w;
        char* KsW = lds + 16384;
        w[0] = (__bf16)lo.x; w[1] = (__bf16)hi.x; *(bf16x2*)(KsW + swz(k_sq + 0, k_c * 4)) = w;
        w[0] = (__bf16)lo.y; w[1] = (__bf16)hi.y; *(bf16x2*)(KsW + swz(k_sq + 1, k_c * 4)) = w;
        w[0] = (__bf16)lo.z; w[1] = (__bf16)hi.z; *(bf16x2*)(KsW + swz(k_sq + 2, k_c * 4)) = w;
        w[0] = (__bf16)lo.w; w[1] = (__bf16)hi.w; *(bf16x2*)(KsW + swz(k_sq + 3, k_c * 4)) = w;
        char* VsW = lds + 32768;
        #pragma unroll
        for (int p = 0; p < 2; ++p) {
            int u  = v_u0 + p;
            int up = (u & 8) | ((u & 3) << 1) | ((u >> 2) & 1);
            float4 f = *(const float4*)(vbase + p * 4);
            bf16x4 hv;
            hv[0] = (__bf16)f.x; hv[1] = (__bf16)f.y;
            hv[2] = (__bf16)f.z; hv[3] = (__bf16)f.w;
            *(bf16x4*)(VsW + swz(v_c, up * 8)) = hv;
        }
    }
    __syncthreads();
    bf16x8 qreg[2][2];
    #pragma unroll
    for (int h = 0; h < 2; ++h)
        #pragma unroll
        for (int kk = 0; kk < 2; ++kk)
            qreg[h][kk] = *(const bf16x8*)(lds + swz(tg * 32 + h * 16 + i, kk * 64 + g * 16));
    f32x4 oacc[2][4];
    #pragma unroll
    for (int h = 0; h < 2; ++h)
        #pragma unroll
        for (int n = 0; n < 4; ++n) oacc[h][n] = (f32x4){0.f, 0.f, 0.f, 0.f};
    float l0 = 0.f, l1 = 0.f;
    for (int kv = 0; kv < NKV; ++kv) {
        const int s0n = (kv + 1 < NKV) ? (kv + 1) * KVBLK : 0;
        float4 klo = *(const float4*)(kbase + s0n);
        float4 khi = *(const float4*)(kbase + T_LEN + s0n);
        float4 vl0 = *(const float4*)(vbase + s0n);
        float4 vl1 = *(const float4*)(vbase + s0n + 4);
        char* KsR = lds + 16384 + (kv & 1) * 8192;
        char* VsR = lds + 32768 + (kv & 1) * 8192;
        f32x4 sacc[2][2];
        #pragma unroll
        for (int h = 0; h < 2; ++h)
            #pragma unroll
            for (int mt = 0; mt < 2; ++mt) sacc[h][mt] = (f32x4){0.f, 0.f, 0.f, 0.f};
        #pragma unroll
        for (int kk = 0; kk < 2; ++kk)
            #pragma unroll
            for (int mt = 0; mt < 2; ++mt) {
                bf16x8 kf = *(const bf16x8*)(KsR + swz(half * 32 + mt * 16 + i, kk * 64 + g * 16));
                sacc[0][mt] = __builtin_amdgcn_mfma_f32_16x16x32_bf16(kf, qreg[0][kk], sacc[0][mt], 0, 0, 0);
                sacc[1][mt] = __builtin_amdgcn_mfma_f32_16x16x32_bf16(kf, qreg[1][kk], sacc[1][mt], 0, 0, 0);
            }
        float rs0 = 0.f, rs1 = 0.f;
        bf16x8 pa0, pa1;
        #pragma unroll
        for (int r = 0; r < 4; ++r) {
            float a0 = EXP2(sacc[0][0][r]);
            float a1 = EXP2(sacc[0][1][r]);
            rs0 += a0 + a1;
            pa0[r] = (__bf16)a0; pa0[4 + r] = (__bf16)a1;
            float b0 = EXP2(sacc[1][0][r]);
            float b1 = EXP2(sacc[1][1][r]);
            rs1 += b0 + b1;
            pa1[r] = (__bf16)b0; pa1[4 + r] = (__bf16)b1;
        }
        #pragma unroll
        for (int n = 0; n < 4; ++n) {
            bf16x8 bv = *(const bf16x8*)(VsR + swz(n * 16 + i, half * 64 + g * 16));
            oacc[0][n] = __builtin_amdgcn_mfma_f32_16x16x32_bf16(pa0, bv, oacc[0][n], 0, 0, 0);
            oacc[1][n] = __builtin_amdgcn_mfma_f32_16x16x32_bf16(pa1, bv, oacc[1][n], 0, 0, 0);
        }
        rs0 += __shfl_xor(rs0, 16); rs0 += __shfl_xor(rs0, 32);
        rs1 += __shfl_xor(rs1, 16); rs1 += __shfl_xor(rs1, 32);
        l0 += rs0; l1 += rs1;
        if (kv + 1 < NKV) {
            char* KsW = lds + 16384 + ((kv + 1) & 1) * 8192;
            char* VsW = lds + 32768 + ((kv + 1) & 1) * 8192;
            bf16x2 w;
            w[0] = (__bf16)klo.x; w[1] = (__bf16)khi.x; *(bf16x2*)(KsW + swz(k_sq + 0, k_c * 4)) = w;
            w[0] = (__bf16)klo.y; w[1] = (__bf16)khi.y; *(bf16x2*)(KsW + swz(k_sq + 1, k_c * 4)) = w;
            w[0] = (__bf16)klo.z; w[1] = (__bf16)khi.z; *(bf16x2*)(KsW + swz(k_sq + 2, k_c * 4)) = w;
            w[0] = (__bf16)klo.w; w[1] = (__bf16)khi.w; *(bf16x2*)(KsW + swz(k_sq + 3, k_c * 4)) = w;
            #pragma unroll
            for (int p = 0; p < 2; ++p) {
                int u  = v_u0 + p;
                int up = (u & 8) | ((u & 3) << 1) | ((u >> 2) & 1);
                float4 f = p ? vl1 : vl0;
                bf16x4 hv;
                hv[0] = (__bf16)f.x; hv[1] = (__bf16)f.y;
                hv[2] = (__bf16)f.z; hv[3] = (__bf16)f.w;
                *(bf16x4*)(VsW + swz(v_c, up * 8)) = hv;
            }
        }
        __syncthreads();
    }
    char* mbase = lds + 32768 + tg * 8192;
    float* lbase = (float*)(lds + 65536);
    if (half == 1) {
        #pragma unroll
        for (int h = 0; h < 2; ++h)
            #pragma unroll
            for (int n = 0; n < 4; ++n)
                *(f32x4*)(mbase + swzM(n * 16 + i, h * 64 + g * 16)) = oacc[h][n];
        if (g == 0) { lbase[tg * 32 + i] = l0; lbase[tg * 32 + 16 + i] = l1; }
    }
    __syncthreads();
    if (half == 0) {
        #pragma unroll
        for (int h = 0; h < 2; ++h)
            #pragma unroll
            for (int n = 0; n < 4; ++n)
                oacc[h][n] += *(const f32x4*)(mbase + swzM(n * 16 + i, h * 64 + g * 16));
        l0 += lbase[tg * 32 + i];
        l1 += lbase[tg * 32 + 16 + i];
        #pragma unroll
        for (int h = 0; h < 2; ++h) {
            float invl = 1.0f / (h ? l1 : l0);
            #pragma unroll
            for (int reg = 0; reg < 4; ++reg) {
                float inv_r = __shfl(invl, g * 4 + reg);
                int t_loc = tg * 32 + h * 16 + g * 4 + reg;
                #pragma unroll
                for (int n = 0; n < 4; ++n) {
                    int c = n * 16 + i;
                    *(float*)(lds + swzO(c, t_loc * 4)) = oacc[h][n][reg] * inv_r;
                }
            }
        }
    }
    __syncthreads();
    #pragma unroll
    for (int it = 0; it < 4; ++it) {
        int idx = it * 512 + tid;
        int c   = idx >> 5;
        int seg = idx & 31;
        float4 u = *(const float4*)(lds + swzO(c, seg * 16));
        *(float4*)(out + (size_t)(bh * 64 + c) * T_LEN + t0 + seg * 4) = u;
    }
}

extern "C" void kernel_launch(void* const* d_in, const int* in_sizes, int n_in,
                              void* d_out, int out_size, void* d_ws, size_t ws_size,
                              hipStream_t stream) {
    const float* qkv = (const float*)d_in[0];
    float* out = (float*)d_out;
    const size_t pan_bytes = (size_t)16 * 64 * 8192;   // 8.39 MB per panel set
    if (ws_size >= 2 * pan_bytes) {
        char* kpan = (char*)d_ws;
        char* vpan = kpan + pan_bytes;
        qkv_prepass<<<dim3(64, 16), 256, 0, stream>>>(qkv, kpan, vpan);
        qkv_attn_glds<<<dim3(512), 512, 0, stream>>>(qkv, out, kpan, vpan);
    } else {
        qkv_attn_fb<<<dim3(512), 512, 0, stream>>>(qkv, out);
    }
}

// Round 16
// 92.086 us; speedup vs baseline: 3.0456x; 1.0487x over previous
//
#include <hip/hip_runtime.h>
#include <hip/hip_bf16.h>

typedef __bf16 bf16x8 __attribute__((ext_vector_type(8)));
typedef __bf16 bf16x4 __attribute__((ext_vector_type(4)));
typedef __bf16 bf16x2 __attribute__((ext_vector_type(2)));
typedef float  f32x4  __attribute__((ext_vector_type(4)));

#define T_LEN 4096
#define QBLK  128
#define NKV   64          // 64-s tiles
#define NIT   32          // 2 tiles per iteration

__device__ __forceinline__ int swz(int row, int colByte) {
    return row * 128 + (colByte ^ (((row ^ (row >> 2)) & 7) << 4));
}
__device__ __forceinline__ int swzM(int row, int colByte) {   // merge buf [c][t] f32
    return row * 128 + (colByte ^ ((row & 7) << 4));
}
__device__ __forceinline__ int swzO(int row, int colByte) {   // epilogue f32 [c][128t]
    return row * 512 + (colByte ^ ((row & 7) << 5));
}

// Q pre-scale: 1/8 (QK scale) x log2(e); no-max exp2 softmax (r9-verified).
#define QSCALE 0.18033688011112042f

#if __has_builtin(__builtin_amdgcn_exp2f)
#define EXP2(x) __builtin_amdgcn_exp2f(x)
#else
__device__ __forceinline__ float EXP2(float x) {
    float r; asm("v_exp_f32 %0, %1" : "=v"(r) : "v"(x)); return r;
}
#endif

__device__ __forceinline__ void glds16(const void* g, void* l) {
    __builtin_amdgcn_global_load_lds(
        (const __attribute__((address_space(1))) void*)g,
        (__attribute__((address_space(3))) void*)l, 16, 0, 0);
}

// ---------------- prepass: K,V -> bf16 swizzled LDS images in d_ws ----------
__global__ __launch_bounds__(256)
void qkv_prepass(const float* __restrict__ qkv, char* __restrict__ kpan,
                 char* __restrict__ vpan) {
    const int tile = blockIdx.x;    // 0..63
    const int bh   = blockIdx.y;    // 0..15
    const float* kp = qkv + ((size_t)bh * 192 + 64)  * T_LEN + tile * 64;
    const float* vp = qkv + ((size_t)bh * 192 + 128) * T_LEN + tile * 64;
    char* kout = kpan + (size_t)(bh * 64 + tile) * 8192;
    char* vout = vpan + (size_t)(bh * 64 + tile) * 8192;

    const int t  = threadIdx.x;
    const int s  = t & 63;
    const int o4 = t >> 6;          // 0..3
    #pragma unroll
    for (int oo = 0; oo < 2; ++oo) {
        const int oct = o4 + oo * 4;                 // c-octet 0..7
        bf16x8 v;
        #pragma unroll
        for (int j = 0; j < 8; ++j)
            v[j] = (__bf16)kp[(size_t)(oct * 8 + j) * T_LEN + s];
        *(bf16x8*)(kout + swz(s, oct * 16)) = v;
    }
    const int c = t & 63;
    #pragma unroll
    for (int p = 0; p < 4; ++p) {
        const int u = o4 * 4 + p;                    // s-chunk 0..15
        float4 f = *(const float4*)(vp + (size_t)c * T_LEN + u * 4);
        const int up = (u & 8) | ((u & 3) << 1) | ((u >> 2) & 1);
        bf16x4 hv;
        hv[0] = (__bf16)f.x; hv[1] = (__bf16)f.y;
        hv[2] = (__bf16)f.z; hv[3] = (__bf16)f.w;
        *(bf16x4*)(vout + swz(c, up * 8)) = hv;
    }
}

// ---------------- main: glds staging, 2 tiles per barrier, 80KiB LDS --------
// LDS map: [0,16K) Qs (dead after qreg hoist; lbase reuse) |
//          [16K,48K) Ks dbuf 2x16K (mbase reuse post-loop) |
//          [48K,80K) Vs dbuf 2x16K.  Epilogue Obuf reuses [0,32K).
__global__ __launch_bounds__(512, 4)
void qkv_attn_glds(const float* __restrict__ qkv, float* __restrict__ out,
                   const char* __restrict__ kpan, const char* __restrict__ vpan) {
    __shared__ __align__(16) char lds[81920];

    const int fid   = (blockIdx.x & 7) * 64 + (blockIdx.x >> 3);   // T1 swizzle
    const int bh    = fid >> 5;
    const int ttile = fid & 31;
    const float* qp = qkv + (size_t)bh * 192 * T_LEN;
    const char* kpb = kpan + (size_t)bh * 64 * 8192;
    const char* vpb = vpan + (size_t)bh * 64 * 8192;
    const int t0 = ttile * QBLK;

    const int tid  = threadIdx.x;
    const int wave = tid >> 6, lane = tid & 63;
    const int g = lane >> 4, i = lane & 15;
    const int tg = wave >> 1, half = wave & 1;   // t-group (32 rows), s-half

    // ---- prologue: async-stage tiles 0,1 into buf0 (overlaps Q staging) ----
    glds16(kpb + tid * 16,        lds + 16384 + wave * 1024);
    glds16(kpb + 8192 + tid * 16, lds + 16384 + 8192 + wave * 1024);
    glds16(vpb + tid * 16,        lds + 49152 + wave * 1024);
    glds16(vpb + 8192 + tid * 16, lds + 49152 + 8192 + wave * 1024);

    // ---- stage Q^T x QSCALE : [128 t][64 c] ----
    {
        const int tq  = (tid & 31) * 4;
        const int cp8 = tid >> 5;
        #pragma unroll
        for (int hh = 0; hh < 2; ++hh) {
            const int cpair = cp8 + hh * 16;
            const float* base = qp + (size_t)(cpair * 2) * T_LEN + t0 + tq;
            float4 lo = *(const float4*)(base);
            float4 hi = *(const float4*)(base + T_LEN);
            bf16x2 v;
            v[0] = (__bf16)(lo.x * QSCALE); v[1] = (__bf16)(hi.x * QSCALE);
            *(bf16x2*)(lds + swz(tq + 0, cpair * 4)) = v;
            v[0] = (__bf16)(lo.y * QSCALE); v[1] = (__bf16)(hi.y * QSCALE);
            *(bf16x2*)(lds + swz(tq + 1, cpair * 4)) = v;
            v[0] = (__bf16)(lo.z * QSCALE); v[1] = (__bf16)(hi.z * QSCALE);
            *(bf16x2*)(lds + swz(tq + 2, cpair * 4)) = v;
            v[0] = (__bf16)(lo.w * QSCALE); v[1] = (__bf16)(hi.w * QSCALE);
            *(bf16x2*)(lds + swz(tq + 3, cpair * 4)) = v;
        }
    }
    __syncthreads();   // Q staged + tiles 0,1 glds drained
    bf16x8 qreg[2][2];   // [t-half][kk], loop-invariant; Qs LDS dead after this
    #pragma unroll
    for (int h = 0; h < 2; ++h)
        #pragma unroll
        for (int kk = 0; kk < 2; ++kk)
            qreg[h][kk] = *(const bf16x8*)(lds + swz(tg * 32 + h * 16 + i, kk * 64 + g * 16));

    f32x4 oacc[2][4];
    #pragma unroll
    for (int h = 0; h < 2; ++h)
        #pragma unroll
        for (int n = 0; n < 4; ++n) oacc[h][n] = (f32x4){0.f, 0.f, 0.f, 0.f};
    float l0 = 0.f, l1 = 0.f;   // lane-local partials; shfl-reduced post-loop

    for (int it = 0; it < NIT; ++it) {
        // ---- async-issue next 2 tiles (land during this iteration's compute) ----
        if (it + 1 < NIT) {
            const size_t off = (size_t)(2 * it + 2) * 8192;
            const int b = (it + 1) & 1;
            glds16(kpb + off + tid * 16,        lds + 16384 + b * 16384 + wave * 1024);
            glds16(kpb + off + 8192 + tid * 16, lds + 16384 + b * 16384 + 8192 + wave * 1024);
            glds16(vpb + off + tid * 16,        lds + 49152 + b * 16384 + wave * 1024);
            glds16(vpb + off + 8192 + tid * 16, lds + 49152 + b * 16384 + 8192 + wave * 1024);
        }
        // ---- two independent tile-chains (compiler interleaves for ILP) ----
        #pragma unroll
        for (int ta = 0; ta < 2; ++ta) {
            char* KsR = lds + 16384 + (it & 1) * 16384 + ta * 8192;
            char* VsR = lds + 49152 + (it & 1) * 16384 + ta * 8192;
            f32x4 sacc[2][2];
            #pragma unroll
            for (int h = 0; h < 2; ++h)
                #pragma unroll
                for (int mt = 0; mt < 2; ++mt) sacc[h][mt] = (f32x4){0.f, 0.f, 0.f, 0.f};
            #pragma unroll
            for (int kk = 0; kk < 2; ++kk)
                #pragma unroll
                for (int mt = 0; mt < 2; ++mt) {
                    bf16x8 kf = *(const bf16x8*)(KsR + swz(half * 32 + mt * 16 + i, kk * 64 + g * 16));
                    sacc[0][mt] = __builtin_amdgcn_mfma_f32_16x16x32_bf16(kf, qreg[0][kk], sacc[0][mt], 0, 0, 0);
                    sacc[1][mt] = __builtin_amdgcn_mfma_f32_16x16x32_bf16(kf, qreg[1][kk], sacc[1][mt], 0, 0, 0);
                }
            bf16x8 pa0, pa1;
            #pragma unroll
            for (int r = 0; r < 4; ++r) {
                float a0 = EXP2(sacc[0][0][r]);
                float a1 = EXP2(sacc[0][1][r]);
                l0 += a0 + a1;
                pa0[r] = (__bf16)a0; pa0[4 + r] = (__bf16)a1;
                float b0 = EXP2(sacc[1][0][r]);
                float b1 = EXP2(sacc[1][1][r]);
                l1 += b0 + b1;
                pa1[r] = (__bf16)b0; pa1[4 + r] = (__bf16)b1;
            }
            #pragma unroll
            for (int n = 0; n < 4; ++n) {
                bf16x8 bv = *(const bf16x8*)(VsR + swz(n * 16 + i, half * 64 + g * 16));
                oacc[0][n] = __builtin_amdgcn_mfma_f32_16x16x32_bf16(pa0, bv, oacc[0][n], 0, 0, 0);
                oacc[1][n] = __builtin_amdgcn_mfma_f32_16x16x32_bf16(pa1, bv, oacc[1][n], 0, 0, 0);
            }
        }
        __syncthreads();   // next bufs ready (drains glds); reads fenced
    }
    // deferred l reduce (linear, once instead of per tile)
    l0 += __shfl_xor(l0, 16); l0 += __shfl_xor(l0, 32);
    l1 += __shfl_xor(l1, 16); l1 += __shfl_xor(l1, 32);

    // ---- merge s-halves (additive), then epilogue ----
    char* mbase = lds + 16384 + tg * 8192;   // [64 c][32 t] f32, swzM (K dbuf dead)
    float* lbase = (float*)(lds);            // Qs region dead
    if (half == 1) {
        #pragma unroll
        for (int h = 0; h < 2; ++h)
            #pragma unroll
            for (int n = 0; n < 4; ++n)
                *(f32x4*)(mbase + swzM(n * 16 + i, h * 64 + g * 16)) = oacc[h][n];
        if (g == 0) { lbase[tg * 32 + i] = l0; lbase[tg * 32 + 16 + i] = l1; }
    }
    __syncthreads();
    if (half == 0) {
        #pragma unroll
        for (int h = 0; h < 2; ++h)
            #pragma unroll
            for (int n = 0; n < 4; ++n)
                oacc[h][n] += *(const f32x4*)(mbase + swzM(n * 16 + i, h * 64 + g * 16));
        l0 += lbase[tg * 32 + i];
        l1 += lbase[tg * 32 + 16 + i];
    }
    __syncthreads();   // merge reads done before Obuf overwrites [0,32K)
    if (half == 0) {
        #pragma unroll
        for (int h = 0; h < 2; ++h) {
            float invl = 1.0f / (h ? l1 : l0);
            #pragma unroll
            for (int reg = 0; reg < 4; ++reg) {
                float inv_r = __shfl(invl, g * 4 + reg);
                int t_loc = tg * 32 + h * 16 + g * 4 + reg;
                #pragma unroll
                for (int n = 0; n < 4; ++n) {
                    int c = n * 16 + i;
                    *(float*)(lds + swzO(c, t_loc * 4)) = oacc[h][n][reg] * inv_r;
                }
            }
        }
    }
    __syncthreads();
    #pragma unroll
    for (int it = 0; it < 4; ++it) {
        int idx = it * 512 + tid;
        int c   = idx >> 5;
        int seg = idx & 31;
        float4 u = *(const float4*)(lds + swzO(c, seg * 16));
        *(float4*)(out + (size_t)(bh * 64 + c) * T_LEN + t0 + seg * 4) = u;
    }
}

// ---------------- fallback (r14 kernel, used when ws_size too small) --------
__global__ __launch_bounds__(512, 4)
void qkv_attn_fb(const float* __restrict__ qkv, float* __restrict__ out) {
    __shared__ __align__(16) char lds[66560];
    const int fid   = (blockIdx.x & 7) * 64 + (blockIdx.x >> 3);
    const int bh    = fid >> 5;
    const int ttile = fid & 31;
    const float* qp = qkv + (size_t)bh * 192 * T_LEN;
    const float* kp = qp + (size_t)64  * T_LEN;
    const float* vp = qp + (size_t)128 * T_LEN;
    const int t0 = ttile * QBLK;
    const int tid  = threadIdx.x;
    const int wave = tid >> 6, lane = tid & 63;
    const int g = lane >> 4, i = lane & 15;
    const int tg = wave >> 1, half = wave & 1;
    const int k_c  = tid >> 4;
    const int k_sq = (tid & 15) * 4;
    const float* kbase = kp + (size_t)(k_c * 2) * T_LEN + k_sq;
    const int v_c  = tid >> 3;
    const int v_u0 = (tid & 7) * 2;
    const float* vbase = vp + (size_t)v_c * T_LEN + v_u0 * 4;
    {
        const int tq  = (tid & 31) * 4;
        const int cp8 = tid >> 5;
        #pragma unroll
        for (int hh = 0; hh < 2; ++hh) {
            const int cpair = cp8 + hh * 16;
            const float* base = qp + (size_t)(cpair * 2) * T_LEN + t0 + tq;
            float4 lo = *(const float4*)(base);
            float4 hi = *(const float4*)(base + T_LEN);
            bf16x2 v;
            v[0] = (__bf16)(lo.x * QSCALE); v[1] = (__bf16)(hi.x * QSCALE);
            *(bf16x2*)(lds + swz(tq + 0, cpair * 4)) = v;
            v[0] = (__bf16)(lo.y * QSCALE); v[1] = (__bf16)(hi.y * QSCALE);
            *(bf16x2*)(lds + swz(tq + 1, cpair * 4)) = v;
            v[0] = (__bf16)(lo.z * QSCALE); v[1] = (__bf16)(hi.z * QSCALE);
            *(bf16x2*)(lds + swz(tq + 2, cpair * 4)) = v;
            v[0] = (__bf16)(lo.w * QSCALE); v[1] = (__bf16)(hi.w * QSCALE);
            *(bf16x2*)(lds + swz(tq + 3, cpair * 4)) = v;
        }
    }
    {
        float4 lo = *(const float4*)(kbase);
        float4 hi = *(const float4*)(kbase + T_LEN);
        bf16x2 w;
        char* KsW = lds + 16384;
        w[0] = (__bf16)lo.x; w[1] = (__bf16)hi.x; *(bf16x2*)(KsW + swz(k_sq + 0, k_c * 4)) = w;
        w[0] = (__bf16)lo.y; w[1] = (__bf16)hi.y; *(bf16x2*)(KsW + swz(k_sq + 1, k_c * 4)) = w;
        w[0] = (__bf16)lo.z; w[1] = (__bf16)hi.z; *(bf16x2*)(KsW + swz(k_sq + 2, k_c * 4)) = w;
        w[0] = (__bf16)lo.w; w[1] = (__bf16)hi.w; *(bf16x2*)(KsW + swz(k_sq + 3, k_c * 4)) = w;
        char* VsW = lds + 32768;
        #pragma unroll
        for (int p = 0; p < 2; ++p) {
            int u  = v_u0 + p;
            int up = (u & 8) | ((u & 3) << 1) | ((u >> 2) & 1);
            float4 f = *(const float4*)(vbase + p * 4);
            bf16x4 hv;
            hv[0] = (__bf16)f.x; hv[1] = (__bf16)f.y;
            hv[2] = (__bf16)f.z; hv[3] = (__bf16)f.w;
            *(bf16x4*)(VsW + swz(v_c, up * 8)) = hv;
        }
    }
    __syncthreads();
    bf16x8 qreg[2][2];
    #pragma unroll
    for (int h = 0; h < 2; ++h)
        #pragma unroll
        for (int kk = 0; kk < 2; ++kk)
            qreg[h][kk] = *(const bf16x8*)(lds + swz(tg * 32 + h * 16 + i, kk * 64 + g * 16));
    f32x4 oacc[2][4];
    #pragma unroll
    for (int h = 0; h < 2; ++h)
        #pragma unroll
        for (int n = 0; n < 4; ++n) oacc[h][n] = (f32x4){0.f, 0.f, 0.f, 0.f};
    float l0 = 0.f, l1 = 0.f;
    for (int kv = 0; kv < 64; ++kv) {
        const int s0n = (kv + 1 < 64) ? (kv + 1) * 64 : 0;
        float4 klo = *(const float4*)(kbase + s0n);
        float4 khi = *(const float4*)(kbase + T_LEN + s0n);
        float4 vl0 = *(const float4*)(vbase + s0n);
        float4 vl1 = *(const float4*)(vbase + s0n + 4);
        char* KsR = lds + 16384 + (kv & 1) * 8192;
        char* VsR = lds + 32768 + (kv & 1) * 8192;
        f32x4 sacc[2][2];
        #pragma unroll
        for (int h = 0; h < 2; ++h)
            #pragma unroll
            for (int mt = 0; mt < 2; ++mt) sacc[h][mt] = (f32x4){0.f, 0.f, 0.f, 0.f};
        #pragma unroll
        for (int kk = 0; kk < 2; ++kk)
            #pragma unroll
            for (int mt = 0; mt < 2; ++mt) {
                bf16x8 kf = *(const bf16x8*)(KsR + swz(half * 32 + mt * 16 + i, kk * 64 + g * 16));
                sacc[0][mt] = __builtin_amdgcn_mfma_f32_16x16x32_bf16(kf, qreg[0][kk], sacc[0][mt], 0, 0, 0);
                sacc[1][mt] = __builtin_amdgcn_mfma_f32_16x16x32_bf16(kf, qreg[1][kk], sacc[1][mt], 0, 0, 0);
            }
        bf16x8 pa0, pa1;
        #pragma unroll
        for (int r = 0; r < 4; ++r) {
            float a0 = EXP2(sacc[0][0][r]);
            float a1 = EXP2(sacc[0][1][r]);
            l0 += a0 + a1;
            pa0[r] = (__bf16)a0; pa0[4 + r] = (__bf16)a1;
            float b0 = EXP2(sacc[1][0][r]);
            float b1 = EXP2(sacc[1][1][r]);
            l1 += b0 + b1;
            pa1[r] = (__bf16)b0; pa1[4 + r] = (__bf16)b1;
        }
        #pragma unroll
        for (int n = 0; n < 4; ++n) {
            bf16x8 bv = *(const bf16x8*)(VsR + swz(n * 16 + i, half * 64 + g * 16));
            oacc[0][n] = __builtin_amdgcn_mfma_f32_16x16x32_bf16(pa0, bv, oacc[0][n], 0, 0, 0);
            oacc[1][n] = __builtin_amdgcn_mfma_f32_16x16x32_bf16(pa1, bv, oacc[1][n], 0, 0, 0);
        }
        if (kv + 1 < 64) {
            char* KsW = lds + 16384 + ((kv + 1) & 1) * 8192;
            char* VsW = lds + 32768 + ((kv + 1) & 1) * 8192;
            bf16x2 w;
            w[0] = (__bf16)klo.x; w[1] = (__bf16)khi.x; *(bf16x2*)(KsW + swz(k_sq + 0, k_c * 4)) = w;
            w[0] = (__bf16)klo.y; w[1] = (__bf16)khi.y; *(bf16x2*)(KsW + swz(k_sq + 1, k_c * 4)) = w;
            w[0] = (__bf16)klo.z; w[1] = (__bf16)khi.z; *(bf16x2*)(KsW + swz(k_sq + 2, k_c * 4)) = w;
            w[0] = (__bf16)klo.w; w[1] = (__bf16)khi.w; *(bf16x2*)(KsW + swz(k_sq + 3, k_c * 4)) = w;
            #pragma unroll
            for (int p = 0; p < 2; ++p) {
                int u  = v_u0 + p;
                int up = (u & 8) | ((u & 3) << 1) | ((u >> 2) & 1);
                float4 f = p ? vl1 : vl0;
                bf16x4 hv;
                hv[0] = (__bf16)f.x; hv[1] = (__bf16)f.y;
                hv[2] = (__bf16)f.z; hv[3] = (__bf16)f.w;
                *(bf16x4*)(VsW + swz(v_c, up * 8)) = hv;
            }
        }
        __syncthreads();
    }
    l0 += __shfl_xor(l0, 16); l0 += __shfl_xor(l0, 32);
    l1 += __shfl_xor(l1, 16); l1 += __shfl_xor(l1, 32);
    char* mbase = lds + 32768 + tg * 8192;
    float* lbase = (float*)(lds + 65536);
    if (half == 1) {
        #pragma unroll
        for (int h = 0; h < 2; ++h)
            #pragma unroll
            for (int n = 0; n < 4; ++n)
                *(f32x4*)(mbase + swzM(n * 16 + i, h * 64 + g * 16)) = oacc[h][n];
        if (g == 0) { lbase[tg * 32 + i] = l0; lbase[tg * 32 + 16 + i] = l1; }
    }
    __syncthreads();
    if (half == 0) {
        #pragma unroll
        for (int h = 0; h < 2; ++h)
            #pragma unroll
            for (int n = 0; n < 4; ++n)
                oacc[h][n] += *(const f32x4*)(mbase + swzM(n * 16 + i, h * 64 + g * 16));
        l0 += lbase[tg * 32 + i];
        l1 += lbase[tg * 32 + 16 + i];
        #pragma unroll
        for (int h = 0; h < 2; ++h) {
            float invl = 1.0f / (h ? l1 : l0);
            #pragma unroll
            for (int reg = 0; reg < 4; ++reg) {
                float inv_r = __shfl(invl, g * 4 + reg);
                int t_loc = tg * 32 + h * 16 + g * 4 + reg;
                #pragma unroll
                for (int n = 0; n < 4; ++n) {
                    int c = n * 16 + i;
                    *(float*)(lds + swzO(c, t_loc * 4)) = oacc[h][n][reg] * inv_r;
                }
            }
        }
    }
    __syncthreads();
    #pragma unroll
    for (int it = 0; it < 4; ++it) {
        int idx = it * 512 + tid;
        int c   = idx >> 5;
        int seg = idx & 31;
        float4 u = *(const float4*)(lds + swzO(c, seg * 16));
        *(float4*)(out + (size_t)(bh * 64 + c) * T_LEN + t0 + seg * 4) = u;
    }
}

extern "C" void kernel_launch(void* const* d_in, const int* in_sizes, int n_in,
                              void* d_out, int out_size, void* d_ws, size_t ws_size,
                              hipStream_t stream) {
    const float* qkv = (const float*)d_in[0];
    float* out = (float*)d_out;
    const size_t pan_bytes = (size_t)16 * 64 * 8192;   // 8.39 MB per panel set
    if (ws_size >= 2 * pan_bytes) {
        char* kpan = (char*)d_ws;
        char* vpan = kpan + pan_bytes;
        qkv_prepass<<<dim3(64, 16), 256, 0, stream>>>(qkv, kpan, vpan);
        qkv_attn_glds<<<dim3(512), 512, 0, stream>>>(qkv, out, kpan, vpan);
    } else {
        qkv_attn_fb<<<dim3(512), 512, 0, stream>>>(qkv, out);
    }
}